// Round 4
// baseline (581.202 us; speedup 1.0000x reference)
//
#include <hip/hip_runtime.h>
#include <hip/hip_bf16.h>
#include <stdint.h>

#define Bb 4
#define Ss 2048
#define Dd 1024
#define Hh 16
#define DK 64
#define BH 64
#define Mm 8192

typedef __attribute__((ext_vector_type(8))) _Float16 f16x8;
typedef __attribute__((ext_vector_type(4))) _Float16 f16x4;
typedef __attribute__((ext_vector_type(4))) float f32x4;

__device__ __forceinline__ void gload16(const _Float16* g, _Float16* lds) {
  __builtin_amdgcn_global_load_lds((const __attribute__((address_space(1))) unsigned int*)g,
                                   (__attribute__((address_space(3))) unsigned int*)lds, 16, 0, 0);
}

// ---------------- K0a: convert activations fp32 -> fp16 ----------------
__global__ __launch_bounds__(256) void cvt_act(const float* __restrict__ q,
                                               const float* __restrict__ k,
                                               const float* __restrict__ v,
                                               _Float16* __restrict__ xq,
                                               _Float16* __restrict__ xk,
                                               _Float16* __restrict__ xv) {
  const float* src = blockIdx.z == 0 ? q : (blockIdx.z == 1 ? k : v);
  _Float16* dst = blockIdx.z == 0 ? xq : (blockIdx.z == 1 ? xk : xv);
  int i = (blockIdx.x * 256 + threadIdx.x) * 8;
  float4 a = *(const float4*)(src + i);
  float4 b = *(const float4*)(src + i + 4);
  union { f16x8 v8; _Float16 h[8]; } o;
  o.h[0] = (_Float16)a.x; o.h[1] = (_Float16)a.y; o.h[2] = (_Float16)a.z; o.h[3] = (_Float16)a.w;
  o.h[4] = (_Float16)b.x; o.h[5] = (_Float16)b.y; o.h[6] = (_Float16)b.z; o.h[7] = (_Float16)b.w;
  *(f16x8*)(dst + i) = o.v8;
}

// ---------------- K0b: convert + transpose weights: Wt[n][k] = f16(W[k][n]) ----------------
__global__ __launch_bounds__(256) void cvt_wt(const float* __restrict__ wq,
                                              const float* __restrict__ wk,
                                              const float* __restrict__ wv,
                                              _Float16* __restrict__ tq,
                                              _Float16* __restrict__ tk,
                                              _Float16* __restrict__ tv) {
  const float* w = blockIdx.z == 0 ? wq : (blockIdx.z == 1 ? wk : wv);
  _Float16* o = blockIdx.z == 0 ? tq : (blockIdx.z == 1 ? tk : tv);
  __shared__ float tile[64][65];
  int k0 = blockIdx.x * 64;
  int n0 = blockIdx.y * 64;
  int t = threadIdx.x;
  int tr = t >> 4;
  int tc = (t & 15) * 4;
  for (int i = 0; i < 4; i++) {
    int r = i * 16 + tr;
    float4 val = *(const float4*)(w + (k0 + r) * Dd + n0 + tc);
    tile[r][tc + 0] = val.x; tile[r][tc + 1] = val.y;
    tile[r][tc + 2] = val.z; tile[r][tc + 3] = val.w;
  }
  __syncthreads();
  for (int i = 0; i < 2; i++) {
    int vdx = t + 256 * i;
    int rn = vdx >> 3;
    int c8 = (vdx & 7) * 8;
    union { f16x8 v8; _Float16 h[8]; } o2;
    for (int j = 0; j < 8; j++) o2.h[j] = (_Float16)tile[c8 + j][rn];
    *(f16x8*)(o + (n0 + rn) * Dd + k0 + c8) = o2.v8;
  }
}

// ---------------- K1: projection GEMM (m97 structure) ----------------
__global__ __launch_bounds__(256) void gemm_qkv(
    const _Float16* __restrict__ xq, const _Float16* __restrict__ xk,
    const _Float16* __restrict__ xv,
    const _Float16* __restrict__ wtq, const _Float16* __restrict__ wtk,
    const _Float16* __restrict__ wtv,
    const float* __restrict__ bq, const float* __restrict__ bk, const float* __restrict__ bv,
    _Float16* __restrict__ oq, _Float16* __restrict__ ok,
    _Float16* __restrict__ ov) {
  int z = blockIdx.z;
  const _Float16* A  = z == 0 ? xq  : (z == 1 ? xk  : xv);
  const _Float16* Bt = z == 0 ? wtq : (z == 1 ? wtk : wtv);
  const float* bias  = z == 0 ? bq  : (z == 1 ? bk  : bv);
  _Float16* out      = z == 0 ? oq  : (z == 1 ? ok  : ov);

  __shared__ _Float16 As[128 * 64];
  __shared__ _Float16 Bs[128 * 64];

  int tid = threadIdx.x;
  int w = tid >> 6;
  int l = tid & 63;
  int lr = l & 15, lk = l >> 4;
  int m0 = blockIdx.x * 128;
  int n0 = blockIdx.y * 128;
  int wr = (w >> 1) * 64;
  int wc = (w & 1) * 64;

  f32x4 acc[4][4] = {};

  for (int kt = 0; kt < Dd; kt += 64) {
    __syncthreads();
    for (int i = 0; i < 4; i++) {
      int fbase = i * 256 + w * 64;     // wave-uniform chunk base
      int f = fbase + l;
      int r = f >> 3, c = (f & 7) * 8;
      gload16(A + (m0 + r) * Dd + kt + c, &As[fbase * 8]);
      gload16(Bt + (n0 + r) * Dd + kt + c, &Bs[fbase * 8]);
    }
    __syncthreads();
    for (int kh = 0; kh < 2; kh++) {
      f16x8 af[4], bfr[4];
      for (int mi = 0; mi < 4; mi++)
        af[mi] = *(const f16x8*)&As[(wr + mi * 16 + lr) * 64 + kh * 32 + lk * 8];
      for (int ni = 0; ni < 4; ni++)
        bfr[ni] = *(const f16x8*)&Bs[(wc + ni * 16 + lr) * 64 + kh * 32 + lk * 8];
      for (int mi = 0; mi < 4; mi++)
        for (int ni = 0; ni < 4; ni++)
          acc[mi][ni] = __builtin_amdgcn_mfma_f32_16x16x32_f16(af[mi], bfr[ni], acc[mi][ni], 0, 0, 0);
    }
  }

  for (int mi = 0; mi < 4; mi++) {
    for (int ni = 0; ni < 4; ni++) {
      int n = n0 + wc + ni * 16 + lr;
      float bval = bias[n];
      int h = n >> 6, dk = n & 63;
      for (int j = 0; j < 4; j++) {
        int m = m0 + wr + mi * 16 + lk * 4 + j;
        int b = m >> 11, s = m & 2047;
        out[((b * Hh + h) * Ss + s) * DK + dk] = (_Float16)(acc[mi][ni][j] + bval);
      }
    }
  }
}

// ---------------- K2: transpose V: [bh][s][dk] -> [bh][dk][s] ----------------
__global__ __launch_bounds__(256) void transpose_v(const unsigned short* __restrict__ vin,
                                                   unsigned short* __restrict__ vout) {
  __shared__ unsigned short t[64][80];
  typedef __attribute__((ext_vector_type(8))) short s16x8;
  int bh = blockIdx.y;
  int s0 = blockIdx.x * 64;
  int tid = threadIdx.x;
  const unsigned short* vp = vin + bh * (Ss * DK);
  for (int i = 0; i < 2; i++) {
    int v = tid + 256 * i;
    int r = v >> 3, c8 = (v & 7) * 8;
    s16x8 val = *(const s16x8*)(vp + (s0 + r) * DK + c8);
    *(s16x8*)&t[r][c8] = val;
  }
  __syncthreads();
  unsigned short* op = vout + bh * (DK * Ss);
  for (int i = 0; i < 2; i++) {
    int v = tid + 256 * i;
    int rn = v >> 3;
    int c8 = (v & 7) * 8;
    union { s16x8 v8; unsigned short u[8]; } o2;
    for (int j = 0; j < 8; j++) o2.u[j] = t[c8 + j][rn];
    *(s16x8*)(op + rn * Ss + s0 + c8) = o2.v8;
  }
}

// ---------------- K3: flash attention (swapped-operand, 16 q-rows/wave, 1-wave blocks) ----------------
// Q,K: [bh][s][64] f16; Vt: [bh][64][s] f16; out fp32 [b,s,1024] = ctx + query
// mfma(K,Q) -> S^T[kv][q]: lane owns q-row q=lr with kv=kg*16+lk*4+j in regs.
// Softmax lane-local + 2 shfl_xor. mfma(Vt,P) -> ctx^T[d][q]; float4 epilogue.
// 8192 one-wave blocks => 8 waves/SIMD of work for latency hiding (TLP).
__global__ __launch_bounds__(64, 6) void attn(const _Float16* __restrict__ Qb,
                                              const _Float16* __restrict__ Kb,
                                              const _Float16* __restrict__ Vt,
                                              const float* __restrict__ query,
                                              float* __restrict__ outp) {
  __shared__ _Float16 Pw[16 * 64];    // 2KB per 1-wave block
  int l = threadIdx.x;
  int lr = l & 15, lk = l >> 4;
  int bh = blockIdx.y;
  int q0 = blockIdx.x * 16;
  const _Float16* Qp = Qb + bh * (Ss * DK);
  const _Float16* Kp = Kb + bh * (Ss * DK);
  const _Float16* Vp = Vt + bh * (DK * Ss);

  // Q fragment as MFMA B-operand: col=q=q0+lr, k=dk=kf*32+lk*8..+7
  f16x8 qf[2];
  for (int kf = 0; kf < 2; kf++)
    qf[kf] = *(const f16x8*)(Qp + (q0 + lr) * DK + kf * 32 + lk * 8);

  f32x4 o[4] = {};        // o[dg]: ctx^T, row d=dg*16+lk*4+j, col q=lr
  float mrun = -1e30f, lrun = 0.f;
  const f32x4 fz = {0.f, 0.f, 0.f, 0.f};
  const int sw = (lr & 7) << 3;   // P swizzle for this lane's q-row

  for (int kv0 = 0; kv0 < Ss; kv0 += 64) {
    // S^T[kv][q]: sc[kg][j] = S[kv=kg*16+lk*4+j][q=lr]
    f32x4 sc[4];
    for (int kg = 0; kg < 4; kg++) {
      const _Float16* kp = Kp + (kv0 + kg * 16 + lr) * DK + lk * 8;
      f16x8 k0 = *(const f16x8*)kp;
      f16x8 k1 = *(const f16x8*)(kp + 32);
      f32x4 t0 = __builtin_amdgcn_mfma_f32_16x16x32_f16(k0, qf[0], fz, 0, 0, 0);
      sc[kg] = __builtin_amdgcn_mfma_f32_16x16x32_f16(k1, qf[1], t0, 0, 0, 0);
    }

    // lane-local online softmax for q-row q=lr
    float pm = fmaxf(fmaxf(sc[0][0], sc[0][1]), fmaxf(sc[0][2], sc[0][3]));
    for (int kg = 1; kg < 4; kg++)
      pm = fmaxf(pm, fmaxf(fmaxf(sc[kg][0], sc[kg][1]), fmaxf(sc[kg][2], sc[kg][3])));
    pm = fmaxf(pm, __shfl_xor(pm, 16));
    pm = fmaxf(pm, __shfl_xor(pm, 32));
    // defer-max (T13): only rescale when the max grew by > 8
    if (!__all(pm - mrun <= 8.f)) {
      float mn = fmaxf(mrun, pm);
      float scale = __expf(mrun - mn);
      mrun = mn;
      lrun *= scale;
      for (int dg = 0; dg < 4; dg++)
        for (int j = 0; j < 4; j++) o[dg][j] *= scale;
    }
    float rs = 0.f;
    for (int kg = 0; kg < 4; kg++) {
      f16x4 pk;
      for (int j = 0; j < 4; j++) {
        float p = __expf(sc[kg][j] - mrun);
        rs += p;
        pk[j] = (_Float16)p;
      }
      int kvb = kg * 16 + lk * 4;
      *(f16x4*)&Pw[lr * 64 + (kvb ^ sw)] = pk;   // ds_write_b64, XOR-swizzled
    }
    rs += __shfl_xor(rs, 16);
    rs += __shfl_xor(rs, 32);
    lrun += rs;

    asm volatile("s_waitcnt lgkmcnt(0)" ::: "memory");
    __builtin_amdgcn_sched_barrier(0);

    // P fragment as MFMA B-operand: col=q=lr, k=kv=kk*32+lk*8..+7
    f16x8 pa[2];
    for (int kk = 0; kk < 2; kk++)
      pa[kk] = *(const f16x8*)&Pw[lr * 64 + ((kk * 32 + lk * 8) ^ sw)];

    // PV swapped: o^T[d][q] += Vt_frag (A: row=d, k=kv) x P_frag (B: col=q, k=kv)
    for (int dg = 0; dg < 4; dg++) {
      const _Float16* vp = Vp + (dg * 16 + lr) * Ss + kv0 + lk * 8;
      f16x8 v0 = *(const f16x8*)vp;
      f16x8 v1 = *(const f16x8*)(vp + 32);
      o[dg] = __builtin_amdgcn_mfma_f32_16x16x32_f16(v0, pa[0], o[dg], 0, 0, 0);
      o[dg] = __builtin_amdgcn_mfma_f32_16x16x32_f16(v1, pa[1], o[dg], 0, 0, 0);
    }
  }

  // epilogue: ctx^T reg layout -> contiguous d per lane -> float4 stores
  int b = bh >> 4, h = bh & 15;
  float inv = 1.f / lrun;
  int qglob = q0 + lr;
  for (int dg = 0; dg < 4; dg++) {
    int d = h * 64 + dg * 16 + lk * 4;
    int idx = (b * Ss + qglob) * Dd + d;
    float4 qv = *(const float4*)(query + idx);
    float4 ov;
    ov.x = o[dg][0] * inv + qv.x;
    ov.y = o[dg][1] * inv + qv.y;
    ov.z = o[dg][2] * inv + qv.z;
    ov.w = o[dg][3] * inv + qv.w;
    *(float4*)(outp + idx) = ov;
  }
}

extern "C" void kernel_launch(void* const* d_in, const int* in_sizes, int n_in,
                              void* d_out, int out_size, void* d_ws, size_t ws_size,
                              hipStream_t stream) {
  const float* query = (const float*)d_in[0];
  const float* key   = (const float*)d_in[1];
  const float* value = (const float*)d_in[2];
  const float* Wq = (const float*)d_in[3];
  const float* bq = (const float*)d_in[4];
  const float* Wk = (const float*)d_in[5];
  const float* bk = (const float*)d_in[6];
  const float* Wv = (const float*)d_in[7];
  const float* bv = (const float*)d_in[8];
  float* out = (float*)d_out;

  _Float16* ws = (_Float16*)d_ws;
  const size_t ACT = (size_t)Mm * Dd;
  const size_t WSZ = (size_t)Dd * Dd;
  _Float16* Xq   = ws;
  _Float16* Xk   = Xq + ACT;
  _Float16* Xv   = Xk + ACT;
  _Float16* Wtq  = Xv + ACT;
  _Float16* Wtk  = Wtq + WSZ;
  _Float16* Wtv  = Wtk + WSZ;
  _Float16* Qb   = Wtv + WSZ;
  _Float16* Kb   = Qb + ACT;
  _Float16* Vtmp = Kb + ACT;
  _Float16* VtT  = Vtmp + ACT;

  cvt_act<<<dim3(4096, 1, 3), dim3(256), 0, stream>>>(query, key, value, Xq, Xk, Xv);
  cvt_wt<<<dim3(16, 16, 3), dim3(256), 0, stream>>>(Wq, Wk, Wv, Wtq, Wtk, Wtv);
  gemm_qkv<<<dim3(64, 8, 3), dim3(256), 0, stream>>>(Xq, Xk, Xv, Wtq, Wtk, Wtv,
                                                     bq, bk, bv, Qb, Kb, Vtmp);
  transpose_v<<<dim3(32, 64), dim3(256), 0, stream>>>((const unsigned short*)Vtmp,
                                                      (unsigned short*)VtT);
  attn<<<dim3(128, 64), dim3(64), 0, stream>>>(Qb, Kb, VtT, query, out);
}

// Round 5
// 381.811 us; speedup vs baseline: 1.5222x; 1.5222x over previous
//
#include <hip/hip_runtime.h>
#include <hip/hip_bf16.h>
#include <stdint.h>

#define Bb 4
#define Ss 2048
#define Dd 1024
#define Hh 16
#define DK 64
#define BH 64
#define Mm 8192

typedef __attribute__((ext_vector_type(8))) _Float16 f16x8;
typedef __attribute__((ext_vector_type(2))) _Float16 f16x2;
typedef __attribute__((ext_vector_type(4))) float f32x4;
typedef __attribute__((ext_vector_type(16))) float f32x16;

__device__ __forceinline__ void gload16(const _Float16* g, _Float16* lds) {
  __builtin_amdgcn_global_load_lds((const __attribute__((address_space(1))) unsigned int*)g,
                                   (__attribute__((address_space(3))) unsigned int*)lds, 16, 0, 0);
}

// pack two f32 -> u32 of 2 f16 (RNE; compiler emits cvt+pack, m240)
__device__ __forceinline__ unsigned pk2(float a, float b) {
  union { f16x2 h; unsigned u; } x;
  x.h[0] = (_Float16)a; x.h[1] = (_Float16)b;
  return x.u;
}

// ---------------- K0a: convert activations fp32 -> fp16 ----------------
__global__ __launch_bounds__(256) void cvt_act(const float* __restrict__ q,
                                               const float* __restrict__ k,
                                               const float* __restrict__ v,
                                               _Float16* __restrict__ xq,
                                               _Float16* __restrict__ xk,
                                               _Float16* __restrict__ xv) {
  const float* src = blockIdx.z == 0 ? q : (blockIdx.z == 1 ? k : v);
  _Float16* dst = blockIdx.z == 0 ? xq : (blockIdx.z == 1 ? xk : xv);
  int i = (blockIdx.x * 256 + threadIdx.x) * 8;
  float4 a = *(const float4*)(src + i);
  float4 b = *(const float4*)(src + i + 4);
  union { f16x8 v8; _Float16 h[8]; } o;
  o.h[0] = (_Float16)a.x; o.h[1] = (_Float16)a.y; o.h[2] = (_Float16)a.z; o.h[3] = (_Float16)a.w;
  o.h[4] = (_Float16)b.x; o.h[5] = (_Float16)b.y; o.h[6] = (_Float16)b.z; o.h[7] = (_Float16)b.w;
  *(f16x8*)(dst + i) = o.v8;
}

// ---------------- K0b: convert + transpose weights: Wt[n][k] = f16(W[k][n]) ----------------
__global__ __launch_bounds__(256) void cvt_wt(const float* __restrict__ wq,
                                              const float* __restrict__ wk,
                                              const float* __restrict__ wv,
                                              _Float16* __restrict__ tq,
                                              _Float16* __restrict__ tk,
                                              _Float16* __restrict__ tv) {
  const float* w = blockIdx.z == 0 ? wq : (blockIdx.z == 1 ? wk : wv);
  _Float16* o = blockIdx.z == 0 ? tq : (blockIdx.z == 1 ? tk : tv);
  __shared__ float tile[64][65];
  int k0 = blockIdx.x * 64;
  int n0 = blockIdx.y * 64;
  int t = threadIdx.x;
  int tr = t >> 4;
  int tc = (t & 15) * 4;
  for (int i = 0; i < 4; i++) {
    int r = i * 16 + tr;
    float4 val = *(const float4*)(w + (k0 + r) * Dd + n0 + tc);
    tile[r][tc + 0] = val.x; tile[r][tc + 1] = val.y;
    tile[r][tc + 2] = val.z; tile[r][tc + 3] = val.w;
  }
  __syncthreads();
  for (int i = 0; i < 2; i++) {
    int vdx = t + 256 * i;
    int rn = vdx >> 3;
    int c8 = (vdx & 7) * 8;
    union { f16x8 v8; _Float16 h[8]; } o2;
    for (int j = 0; j < 8; j++) o2.h[j] = (_Float16)tile[c8 + j][rn];
    *(f16x8*)(o + (n0 + rn) * Dd + k0 + c8) = o2.v8;
  }
}

// ---------------- K1: projection GEMM (m97 structure) ----------------
__global__ __launch_bounds__(256) void gemm_qkv(
    const _Float16* __restrict__ xq, const _Float16* __restrict__ xk,
    const _Float16* __restrict__ xv,
    const _Float16* __restrict__ wtq, const _Float16* __restrict__ wtk,
    const _Float16* __restrict__ wtv,
    const float* __restrict__ bq, const float* __restrict__ bk, const float* __restrict__ bv,
    _Float16* __restrict__ oq, _Float16* __restrict__ ok,
    _Float16* __restrict__ ov) {
  int z = blockIdx.z;
  const _Float16* A  = z == 0 ? xq  : (z == 1 ? xk  : xv);
  const _Float16* Bt = z == 0 ? wtq : (z == 1 ? wtk : wtv);
  const float* bias  = z == 0 ? bq  : (z == 1 ? bk  : bv);
  _Float16* out      = z == 0 ? oq  : (z == 1 ? ok  : ov);

  __shared__ _Float16 As[128 * 64];
  __shared__ _Float16 Bs[128 * 64];

  int tid = threadIdx.x;
  int w = tid >> 6;
  int l = tid & 63;
  int lr = l & 15, lk = l >> 4;
  int m0 = blockIdx.x * 128;
  int n0 = blockIdx.y * 128;
  int wr = (w >> 1) * 64;
  int wc = (w & 1) * 64;

  f32x4 acc[4][4] = {};

  for (int kt = 0; kt < Dd; kt += 64) {
    __syncthreads();
    for (int i = 0; i < 4; i++) {
      int fbase = i * 256 + w * 64;     // wave-uniform chunk base
      int f = fbase + l;
      int r = f >> 3, c = (f & 7) * 8;
      gload16(A + (m0 + r) * Dd + kt + c, &As[fbase * 8]);
      gload16(Bt + (n0 + r) * Dd + kt + c, &Bs[fbase * 8]);
    }
    __syncthreads();
    for (int kh = 0; kh < 2; kh++) {
      f16x8 af[4], bfr[4];
      for (int mi = 0; mi < 4; mi++)
        af[mi] = *(const f16x8*)&As[(wr + mi * 16 + lr) * 64 + kh * 32 + lk * 8];
      for (int ni = 0; ni < 4; ni++)
        bfr[ni] = *(const f16x8*)&Bs[(wc + ni * 16 + lr) * 64 + kh * 32 + lk * 8];
      for (int mi = 0; mi < 4; mi++)
        for (int ni = 0; ni < 4; ni++)
          acc[mi][ni] = __builtin_amdgcn_mfma_f32_16x16x32_f16(af[mi], bfr[ni], acc[mi][ni], 0, 0, 0);
    }
  }

  for (int mi = 0; mi < 4; mi++) {
    for (int ni = 0; ni < 4; ni++) {
      int n = n0 + wc + ni * 16 + lr;
      float bval = bias[n];
      int h = n >> 6, dk = n & 63;
      for (int j = 0; j < 4; j++) {
        int m = m0 + wr + mi * 16 + lk * 4 + j;
        int b = m >> 11, s = m & 2047;
        out[((b * Hh + h) * Ss + s) * DK + dk] = (_Float16)(acc[mi][ni][j] + bval);
      }
    }
  }
}

// ---------------- K2: transpose V: [bh][s][dk] -> [bh][dk][s] ----------------
__global__ __launch_bounds__(256) void transpose_v(const unsigned short* __restrict__ vin,
                                                   unsigned short* __restrict__ vout) {
  __shared__ unsigned short t[64][80];
  typedef __attribute__((ext_vector_type(8))) short s16x8;
  int bh = blockIdx.y;
  int s0 = blockIdx.x * 64;
  int tid = threadIdx.x;
  const unsigned short* vp = vin + bh * (Ss * DK);
  for (int i = 0; i < 2; i++) {
    int v = tid + 256 * i;
    int r = v >> 3, c8 = (v & 7) * 8;
    s16x8 val = *(const s16x8*)(vp + (s0 + r) * DK + c8);
    *(s16x8*)&t[r][c8] = val;
  }
  __syncthreads();
  unsigned short* op = vout + bh * (DK * Ss);
  for (int i = 0; i < 2; i++) {
    int v = tid + 256 * i;
    int rn = v >> 3;
    int c8 = (v & 7) * 8;
    union { s16x8 v8; unsigned short u[8]; } o2;
    for (int j = 0; j < 8; j++) o2.u[j] = t[c8 + j][rn];
    *(s16x8*)(op + rn * Ss + s0 + c8) = o2.v8;
  }
}

// ---------------- K3: flash attention, 32x32x16 MFMA, P fully in-register ----------------
// Q,K: [bh][s][64] f16; Vt: [bh][64][s] f16; out fp32 [b,s,1024] = ctx + query.
// QK swapped: S^T = mfma_32x32(K, Q). C-layout: col=q=lane&31, row=kv=(r&3)+8*(r>>2)+4*hi.
// Each lane owns half of q-row (32 kv values in regs); other half in lane^32.
// Softmax: in-lane tree + 1 shfl_xor(32). P->PV B-operand via f16 packs + shfl_xor(32)
// cross-half exchange (no LDS, no barriers anywhere).
// PV swapped: ctx^T = mfma_32x32(Vt, P). Epilogue: float4 stores of ctx*inv + query.
__global__ __launch_bounds__(256) void attn(const _Float16* __restrict__ Qb,
                                            const _Float16* __restrict__ Kb,
                                            const _Float16* __restrict__ Vt,
                                            const float* __restrict__ query,
                                            float* __restrict__ outp) {
  int tid = threadIdx.x;
  int w = tid >> 6;
  int l31 = tid & 31;
  int hi = (tid >> 5) & 1;
  int bh = blockIdx.x;                 // gridDim.x=64 -> flat%8 = bh%8: per-XCD head locality
  int q0 = blockIdx.y * 128 + w * 32;
  const _Float16* Qp = Qb + bh * (Ss * DK);
  const _Float16* Kp = Kb + bh * (Ss * DK);
  const _Float16* Vp = Vt + bh * (DK * Ss);

  // Q as B-operand: col=q=q0+l31, k=dk=sdk*16+hi*8+i
  f16x8 qf[4];
#pragma unroll
  for (int s = 0; s < 4; s++)
    qf[s] = *(const f16x8*)(Qp + (q0 + l31) * DK + s * 16 + hi * 8);

  f32x16 o0 = {}, o1 = {};    // ctx^T: row d=dg*32+(r&3)+8*(r>>2)+4*hi, col q=l31
  float mrun = -1e30f, lrun = 0.f;

  const _Float16* vrow0 = Vp + l31 * Ss + hi * 8;          // d = l31
  const _Float16* vrow1 = vrow0 + 32 * Ss;                  // d = 32 + l31

  for (int kv0 = 0; kv0 < Ss; kv0 += 64) {
    // ---- QK^T (swapped): A=K rows kv, k=dk ----
    const _Float16* kr0 = Kp + (kv0 + l31) * DK + hi * 8;
    const _Float16* kr1 = kr0 + 32 * DK;
    f32x16 s0 = {}, s1 = {};
#pragma unroll
    for (int sdk = 0; sdk < 4; sdk++) {
      f16x8 ka = *(const f16x8*)(kr0 + sdk * 16);
      s0 = __builtin_amdgcn_mfma_f32_32x32x16_f16(ka, qf[sdk], s0, 0, 0, 0);
    }
#pragma unroll
    for (int sdk = 0; sdk < 4; sdk++) {
      f16x8 kb = *(const f16x8*)(kr1 + sdk * 16);
      s1 = __builtin_amdgcn_mfma_f32_32x32x16_f16(kb, qf[sdk], s1, 0, 0, 0);
    }

    // ---- online softmax: lane owns q=l31 (half the kv; other half at lane^32) ----
    float mx[16];
#pragma unroll
    for (int r = 0; r < 16; r++) mx[r] = fmaxf(s0[r], s1[r]);
#pragma unroll
    for (int d = 8; d >= 1; d >>= 1)
#pragma unroll
      for (int r = 0; r < 8; r++) if (r < d) mx[r] = fmaxf(mx[r], mx[r + d]);
    float pm = fmaxf(mx[0], __shfl_xor(mx[0], 32));

    if (!__all(pm - mrun <= 8.f)) {        // defer-max (T13)
      float mn = fmaxf(mrun, pm);
      float sc_ = __expf(mrun - mn);
      mrun = mn;
      lrun *= sc_;
#pragma unroll
      for (int r = 0; r < 16; r++) { o0[r] *= sc_; o1[r] *= sc_; }
    }

    float sm[16];
#pragma unroll
    for (int r = 0; r < 16; r++) {
      s0[r] = __expf(s0[r] - mrun);
      s1[r] = __expf(s1[r] - mrun);
      sm[r] = s0[r] + s1[r];
    }
#pragma unroll
    for (int d = 8; d >= 1; d >>= 1)
#pragma unroll
      for (int r = 0; r < 8; r++) if (r < d) sm[r] += sm[r + d];
    lrun += sm[0] + __shfl_xor(sm[0], 32);

    // ---- PV (swapped): per 16-kv step, build P B-frag in regs, 2 MFMA (dg=0,1) ----
    // B-frag words w0..w3 = f16 pairs at kv = base+8*hi+{0..7}:
    //   hi=0: w0,w1=own a0,a1   w2,w3=partner a0,a1
    //   hi=1: w0,w1=partner b0,b1  w2,w3=own b0,b1
#define PVSTEP(PV, SIDX)                                                        \
    {                                                                           \
      unsigned a0 = pk2(PV[((SIDX)&1) * 8 + 0], PV[((SIDX)&1) * 8 + 1]);        \
      unsigned a1 = pk2(PV[((SIDX)&1) * 8 + 2], PV[((SIDX)&1) * 8 + 3]);        \
      unsigned b0 = pk2(PV[((SIDX)&1) * 8 + 4], PV[((SIDX)&1) * 8 + 5]);        \
      unsigned b1 = pk2(PV[((SIDX)&1) * 8 + 6], PV[((SIDX)&1) * 8 + 7]);        \
      unsigned xa0 = __shfl_xor(a0, 32), xb0 = __shfl_xor(b0, 32);              \
      unsigned xa1 = __shfl_xor(a1, 32), xb1 = __shfl_xor(b1, 32);              \
      union { unsigned u[4]; f16x8 v; } pf;                                     \
      pf.u[0] = hi ? xb0 : a0;                                                  \
      pf.u[1] = hi ? xb1 : a1;                                                  \
      pf.u[2] = hi ? b0 : xa0;                                                  \
      pf.u[3] = hi ? b1 : xa1;                                                  \
      f16x8 v0 = *(const f16x8*)(vrow0 + kv0 + (SIDX) * 16);                    \
      f16x8 v1 = *(const f16x8*)(vrow1 + kv0 + (SIDX) * 16);                    \
      o0 = __builtin_amdgcn_mfma_f32_32x32x16_f16(v0, pf.v, o0, 0, 0, 0);       \
      o1 = __builtin_amdgcn_mfma_f32_32x32x16_f16(v1, pf.v, o1, 0, 0, 0);       \
    }
    PVSTEP(s0, 0)
    PVSTEP(s0, 1)
    PVSTEP(s1, 2)
    PVSTEP(s1, 3)
#undef PVSTEP
  }

  // ---- epilogue: lane q=q0+l31; d = dg*32 + rq*8 + hi*4 + j ----
  int b = bh >> 4, h = bh & 15;
  float inv = 1.f / lrun;
  int base = (b * Ss + q0 + l31) * Dd + h * 64;
#pragma unroll
  for (int rq = 0; rq < 4; rq++) {
    int d0 = rq * 8 + hi * 4;
    float4 qv0 = *(const float4*)(query + base + d0);
    float4 ov0;
    ov0.x = o0[rq * 4 + 0] * inv + qv0.x;
    ov0.y = o0[rq * 4 + 1] * inv + qv0.y;
    ov0.z = o0[rq * 4 + 2] * inv + qv0.z;
    ov0.w = o0[rq * 4 + 3] * inv + qv0.w;
    *(float4*)(outp + base + d0) = ov0;
    float4 qv1 = *(const float4*)(query + base + 32 + d0);
    float4 ov1;
    ov1.x = o1[rq * 4 + 0] * inv + qv1.x;
    ov1.y = o1[rq * 4 + 1] * inv + qv1.y;
    ov1.z = o1[rq * 4 + 2] * inv + qv1.z;
    ov1.w = o1[rq * 4 + 3] * inv + qv1.w;
    *(float4*)(outp + base + 32 + d0) = ov1;
  }
}

extern "C" void kernel_launch(void* const* d_in, const int* in_sizes, int n_in,
                              void* d_out, int out_size, void* d_ws, size_t ws_size,
                              hipStream_t stream) {
  const float* query = (const float*)d_in[0];
  const float* key   = (const float*)d_in[1];
  const float* value = (const float*)d_in[2];
  const float* Wq = (const float*)d_in[3];
  const float* bq = (const float*)d_in[4];
  const float* Wk = (const float*)d_in[5];
  const float* bk = (const float*)d_in[6];
  const float* Wv = (const float*)d_in[7];
  const float* bv = (const float*)d_in[8];
  float* out = (float*)d_out;

  _Float16* ws = (_Float16*)d_ws;
  const size_t ACT = (size_t)Mm * Dd;
  const size_t WSZ = (size_t)Dd * Dd;
  _Float16* Xq   = ws;
  _Float16* Xk   = Xq + ACT;
  _Float16* Xv   = Xk + ACT;
  _Float16* Wtq  = Xv + ACT;
  _Float16* Wtk  = Wtq + WSZ;
  _Float16* Wtv  = Wtk + WSZ;
  _Float16* Qb   = Wtv + WSZ;
  _Float16* Kb   = Qb + ACT;
  _Float16* Vtmp = Kb + ACT;
  _Float16* VtT  = Vtmp + ACT;

  cvt_act<<<dim3(4096, 1, 3), dim3(256), 0, stream>>>(query, key, value, Xq, Xk, Xv);
  cvt_wt<<<dim3(16, 16, 3), dim3(256), 0, stream>>>(Wq, Wk, Wv, Wtq, Wtk, Wtv);
  gemm_qkv<<<dim3(64, 8, 3), dim3(256), 0, stream>>>(Xq, Xk, Xv, Wtq, Wtk, Wtv,
                                                     bq, bk, bv, Qb, Kb, Vtmp);
  transpose_v<<<dim3(32, 64), dim3(256), 0, stream>>>((const unsigned short*)Vtmp,
                                                      (unsigned short*)VtT);
  attn<<<dim3(64, 16), dim3(256), 0, stream>>>(Qb, Kb, VtT, query, out);
}

// Round 6
// 351.104 us; speedup vs baseline: 1.6554x; 1.0875x over previous
//
#include <hip/hip_runtime.h>
#include <hip/hip_bf16.h>
#include <stdint.h>

#define Bb 4
#define Ss 2048
#define Dd 1024
#define Hh 16
#define DK 64
#define BH 64
#define Mm 8192

typedef __attribute__((ext_vector_type(8))) _Float16 f16x8;
typedef __attribute__((ext_vector_type(2))) _Float16 f16x2;
typedef __attribute__((ext_vector_type(4))) float f32x4;
typedef __attribute__((ext_vector_type(16))) float f32x16;
typedef __attribute__((ext_vector_type(2))) unsigned uint2v;

__device__ __forceinline__ void gload16(const _Float16* g, _Float16* lds) {
  __builtin_amdgcn_global_load_lds((const __attribute__((address_space(1))) unsigned int*)g,
                                   (__attribute__((address_space(3))) unsigned int*)lds, 16, 0, 0);
}

// pack two f32 -> u32 of 2 f16 (RNE)
__device__ __forceinline__ unsigned pk2(float a, float b) {
  union { f16x2 h; unsigned u; } x;
  x.h[0] = (_Float16)a; x.h[1] = (_Float16)b;
  return x.u;
}

// ---------------- K0a: convert activations fp32 -> fp16 ----------------
__global__ __launch_bounds__(256) void cvt_act(const float* __restrict__ q,
                                               const float* __restrict__ k,
                                               const float* __restrict__ v,
                                               _Float16* __restrict__ xq,
                                               _Float16* __restrict__ xk,
                                               _Float16* __restrict__ xv) {
  const float* src = blockIdx.z == 0 ? q : (blockIdx.z == 1 ? k : v);
  _Float16* dst = blockIdx.z == 0 ? xq : (blockIdx.z == 1 ? xk : xv);
  int i = (blockIdx.x * 256 + threadIdx.x) * 8;
  float4 a = *(const float4*)(src + i);
  float4 b = *(const float4*)(src + i + 4);
  union { f16x8 v8; _Float16 h[8]; } o;
  o.h[0] = (_Float16)a.x; o.h[1] = (_Float16)a.y; o.h[2] = (_Float16)a.z; o.h[3] = (_Float16)a.w;
  o.h[4] = (_Float16)b.x; o.h[5] = (_Float16)b.y; o.h[6] = (_Float16)b.z; o.h[7] = (_Float16)b.w;
  *(f16x8*)(dst + i) = o.v8;
}

// ---------------- K0b: convert + transpose weights: Wt[n][k] = f16(W[k][n]) ----------------
__global__ __launch_bounds__(256) void cvt_wt(const float* __restrict__ wq,
                                              const float* __restrict__ wk,
                                              const float* __restrict__ wv,
                                              _Float16* __restrict__ tq,
                                              _Float16* __restrict__ tk,
                                              _Float16* __restrict__ tv) {
  const float* w = blockIdx.z == 0 ? wq : (blockIdx.z == 1 ? wk : wv);
  _Float16* o = blockIdx.z == 0 ? tq : (blockIdx.z == 1 ? tk : tv);
  __shared__ float tile[64][65];
  int k0 = blockIdx.x * 64;
  int n0 = blockIdx.y * 64;
  int t = threadIdx.x;
  int tr = t >> 4;
  int tc = (t & 15) * 4;
  for (int i = 0; i < 4; i++) {
    int r = i * 16 + tr;
    float4 val = *(const float4*)(w + (k0 + r) * Dd + n0 + tc);
    tile[r][tc + 0] = val.x; tile[r][tc + 1] = val.y;
    tile[r][tc + 2] = val.z; tile[r][tc + 3] = val.w;
  }
  __syncthreads();
  for (int i = 0; i < 2; i++) {
    int vdx = t + 256 * i;
    int rn = vdx >> 3;
    int c8 = (vdx & 7) * 8;
    union { f16x8 v8; _Float16 h[8]; } o2;
    for (int j = 0; j < 8; j++) o2.h[j] = (_Float16)tile[c8 + j][rn];
    *(f16x8*)(o + (n0 + rn) * Dd + k0 + c8) = o2.v8;
  }
}

// ---------------- K1: projection GEMM (m97 structure) ----------------
__global__ __launch_bounds__(256) void gemm_qkv(
    const _Float16* __restrict__ xq, const _Float16* __restrict__ xk,
    const _Float16* __restrict__ xv,
    const _Float16* __restrict__ wtq, const _Float16* __restrict__ wtk,
    const _Float16* __restrict__ wtv,
    const float* __restrict__ bq, const float* __restrict__ bk, const float* __restrict__ bv,
    _Float16* __restrict__ oq, _Float16* __restrict__ ok,
    _Float16* __restrict__ ov) {
  int z = blockIdx.z;
  const _Float16* A  = z == 0 ? xq  : (z == 1 ? xk  : xv);
  const _Float16* Bt = z == 0 ? wtq : (z == 1 ? wtk : wtv);
  const float* bias  = z == 0 ? bq  : (z == 1 ? bk  : bv);
  _Float16* out      = z == 0 ? oq  : (z == 1 ? ok  : ov);

  __shared__ _Float16 As[128 * 64];
  __shared__ _Float16 Bs[128 * 64];

  int tid = threadIdx.x;
  int w = tid >> 6;
  int l = tid & 63;
  int lr = l & 15, lk = l >> 4;
  int m0 = blockIdx.x * 128;
  int n0 = blockIdx.y * 128;
  int wr = (w >> 1) * 64;
  int wc = (w & 1) * 64;

  f32x4 acc[4][4] = {};

  for (int kt = 0; kt < Dd; kt += 64) {
    __syncthreads();
    for (int i = 0; i < 4; i++) {
      int fbase = i * 256 + w * 64;     // wave-uniform chunk base
      int f = fbase + l;
      int r = f >> 3, c = (f & 7) * 8;
      gload16(A + (m0 + r) * Dd + kt + c, &As[fbase * 8]);
      gload16(Bt + (n0 + r) * Dd + kt + c, &Bs[fbase * 8]);
    }
    __syncthreads();
    for (int kh = 0; kh < 2; kh++) {
      f16x8 af[4], bfr[4];
      for (int mi = 0; mi < 4; mi++)
        af[mi] = *(const f16x8*)&As[(wr + mi * 16 + lr) * 64 + kh * 32 + lk * 8];
      for (int ni = 0; ni < 4; ni++)
        bfr[ni] = *(const f16x8*)&Bs[(wc + ni * 16 + lr) * 64 + kh * 32 + lk * 8];
      for (int mi = 0; mi < 4; mi++)
        for (int ni = 0; ni < 4; ni++)
          acc[mi][ni] = __builtin_amdgcn_mfma_f32_16x16x32_f16(af[mi], bfr[ni], acc[mi][ni], 0, 0, 0);
    }
  }

  for (int mi = 0; mi < 4; mi++) {
    for (int ni = 0; ni < 4; ni++) {
      int n = n0 + wc + ni * 16 + lr;
      float bval = bias[n];
      int h = n >> 6, dk = n & 63;
      for (int j = 0; j < 4; j++) {
        int m = m0 + wr + mi * 16 + lk * 4 + j;
        int b = m >> 11, s = m & 2047;
        out[((b * Hh + h) * Ss + s) * DK + dk] = (_Float16)(acc[mi][ni][j] + bval);
      }
    }
  }
}

// ---------------- K2: transpose V: [bh][s][dk] -> [bh][dk][s] ----------------
__global__ __launch_bounds__(256) void transpose_v(const unsigned short* __restrict__ vin,
                                                   unsigned short* __restrict__ vout) {
  __shared__ unsigned short t[64][80];
  typedef __attribute__((ext_vector_type(8))) short s16x8;
  int bh = blockIdx.y;
  int s0 = blockIdx.x * 64;
  int tid = threadIdx.x;
  const unsigned short* vp = vin + bh * (Ss * DK);
  for (int i = 0; i < 2; i++) {
    int v = tid + 256 * i;
    int r = v >> 3, c8 = (v & 7) * 8;
    s16x8 val = *(const s16x8*)(vp + (s0 + r) * DK + c8);
    *(s16x8*)&t[r][c8] = val;
  }
  __syncthreads();
  unsigned short* op = vout + bh * (DK * Ss);
  for (int i = 0; i < 2; i++) {
    int v = tid + 256 * i;
    int rn = v >> 3;
    int c8 = (v & 7) * 8;
    union { s16x8 v8; unsigned short u[8]; } o2;
    for (int j = 0; j < 8; j++) o2.u[j] = t[c8 + j][rn];
    *(s16x8*)(op + rn * Ss + s0 + c8) = o2.v8;
  }
}

// ---------------- K3: flash attention, 32x32x16, software-pipelined, P in-register ----------------
// Q,K: [bh][s][64] f16; Vt: [bh][64][s] f16; out fp32 [b,s,1024] = ctx + query.
// kv-tile = 32. Per tile: QK(4 MFMA, consumes kreg) -> issue K loads (t+1) -> issue V
// loads (t) -> softmax VALU (covers load latency) -> pack+permlane32_swap -> PV(4 MFMA).
// No LDS, no barriers. 2048 blocks x 2 waves; 128-VGPR budget = 4 waves/SIMD resident.
__global__ __launch_bounds__(128, 4) void attn(const _Float16* __restrict__ Qb,
                                               const _Float16* __restrict__ Kb,
                                               const _Float16* __restrict__ Vt,
                                               const float* __restrict__ query,
                                               float* __restrict__ outp) {
  int tid = threadIdx.x;
  int w = tid >> 6;
  int l31 = tid & 31;
  int hi = (tid >> 5) & 1;
  int bh = blockIdx.x;                 // gridDim.x=64 -> flat%8 = bh%8: per-XCD head locality
  int q0 = blockIdx.y * 64 + w * 32;
  const _Float16* Qp = Qb + bh * (Ss * DK);
  const _Float16* Kp = Kb + bh * (Ss * DK);
  const _Float16* Vp = Vt + bh * (DK * Ss);

  // Q as B-operand: col=q=q0+l31, k=dk=s*16+hi*8+i
  f16x8 qf[4];
#pragma unroll
  for (int s = 0; s < 4; s++)
    qf[s] = *(const f16x8*)(Qp + (q0 + l31) * DK + s * 16 + hi * 8);

  f32x16 o0 = {}, o1 = {};    // ctx^T: row d=dg*32+(r&3)+8*(r>>2)+4*hi, col q=l31
  float mrun = -1e30f, lrun = 0.f;

  const _Float16* krow = Kp + l31 * DK + hi * 8;       // + kv*DK walks kv
  const _Float16* vr0 = Vp + l31 * Ss + hi * 8;        // d = l31
  const _Float16* vr1 = vr0 + 32 * Ss;                 // d = 32 + l31

  // prologue: K tile 0 into regs
  f16x8 kreg[4];
#pragma unroll
  for (int s = 0; s < 4; s++)
    kreg[s] = *(const f16x8*)(krow + s * 16);

  for (int kv0 = 0; kv0 < Ss; kv0 += 32) {
    // ---- QK^T (swapped): S^T[kv][q], lane owns q=l31, rows (r&3)+8*(r>>2)+4*hi ----
    f32x16 sc = {};
#pragma unroll
    for (int s = 0; s < 4; s++)
      sc = __builtin_amdgcn_mfma_f32_32x32x16_f16(kreg[s], qf[s], sc, 0, 0, 0);

    // ---- prefetch next K tile (always; last overreads 4KB into adjacent ws buffer) ----
    {
      const _Float16* kn = krow + (kv0 + 32) * DK;
#pragma unroll
      for (int s = 0; s < 4; s++)
        kreg[s] = *(const f16x8*)(kn + s * 16);
    }
    // ---- issue V loads for this tile ----
    f16x8 vreg0 = *(const f16x8*)(vr0 + kv0);          // kstep0, d 0..31
    f16x8 vreg1 = *(const f16x8*)(vr1 + kv0);          // kstep0, d 32..63
    f16x8 vreg2 = *(const f16x8*)(vr0 + kv0 + 16);     // kstep1, d 0..31
    f16x8 vreg3 = *(const f16x8*)(vr1 + kv0 + 16);     // kstep1, d 32..63

    // ---- online softmax (lane-local; covers the load latency above) ----
    float m8[8];
#pragma unroll
    for (int r = 0; r < 8; r++) m8[r] = fmaxf(sc[r], sc[r + 8]);
#pragma unroll
    for (int d = 4; d >= 1; d >>= 1)
#pragma unroll
      for (int r = 0; r < 4; r++) if (r < d) m8[r] = fmaxf(m8[r], m8[r + d]);
    float pm = fmaxf(m8[0], __shfl_xor(m8[0], 32));

    if (!__all(pm - mrun <= 8.f)) {        // defer-max (T13)
      float mn = fmaxf(mrun, pm);
      float sc_ = __expf(mrun - mn);
      mrun = mn;
      lrun *= sc_;
#pragma unroll
      for (int r = 0; r < 16; r++) { o0[r] *= sc_; o1[r] *= sc_; }
    }
#pragma unroll
    for (int r = 0; r < 16; r++) sc[r] = __expf(sc[r] - mrun);
    float sm[8];
#pragma unroll
    for (int r = 0; r < 8; r++) sm[r] = sc[r] + sc[r + 8];
#pragma unroll
    for (int d = 4; d >= 1; d >>= 1)
#pragma unroll
      for (int r = 0; r < 4; r++) if (r < d) sm[r] += sm[r + d];
    lrun += sm[0] + __shfl_xor(sm[0], 32);

    // ---- pack P + cross-half exchange (permlane32_swap) + PV MFMA ----
    // step kstep: B-frag words: w0=swap(a0,b0).x w1=swap(a1,b1).x w2=swap(a0,b0).y w3=swap(a1,b1).y
#define PVSTEP(OFF, V0, V1)                                                     \
    {                                                                           \
      unsigned a0 = pk2(sc[(OFF) + 0], sc[(OFF) + 1]);                          \
      unsigned a1 = pk2(sc[(OFF) + 2], sc[(OFF) + 3]);                          \
      unsigned b0 = pk2(sc[(OFF) + 4], sc[(OFF) + 5]);                          \
      unsigned b1 = pk2(sc[(OFF) + 6], sc[(OFF) + 7]);                          \
      uint2v r0 = __builtin_amdgcn_permlane32_swap(a0, b0, false, false);       \
      uint2v r1 = __builtin_amdgcn_permlane32_swap(a1, b1, false, false);       \
      union { unsigned u[4]; f16x8 v; } pf;                                     \
      pf.u[0] = r0[0]; pf.u[1] = r1[0]; pf.u[2] = r0[1]; pf.u[3] = r1[1];       \
      o0 = __builtin_amdgcn_mfma_f32_32x32x16_f16(V0, pf.v, o0, 0, 0, 0);       \
      o1 = __builtin_amdgcn_mfma_f32_32x32x16_f16(V1, pf.v, o1, 0, 0, 0);       \
    }
    PVSTEP(0, vreg0, vreg1)
    PVSTEP(8, vreg2, vreg3)
#undef PVSTEP
  }

  // ---- epilogue: lane q=q0+l31; d = dg*32 + rq*8 + hi*4 + j ----
  int b = bh >> 4, h = bh & 15;
  float inv = 1.f / lrun;
  int base = (b * Ss + q0 + l31) * Dd + h * 64;
#pragma unroll
  for (int rq = 0; rq < 4; rq++) {
    int d0 = rq * 8 + hi * 4;
    float4 qv0 = *(const float4*)(query + base + d0);
    float4 ov0;
    ov0.x = o0[rq * 4 + 0] * inv + qv0.x;
    ov0.y = o0[rq * 4 + 1] * inv + qv0.y;
    ov0.z = o0[rq * 4 + 2] * inv + qv0.z;
    ov0.w = o0[rq * 4 + 3] * inv + qv0.w;
    *(float4*)(outp + base + d0) = ov0;
    float4 qv1 = *(const float4*)(query + base + 32 + d0);
    float4 ov1;
    ov1.x = o1[rq * 4 + 0] * inv + qv1.x;
    ov1.y = o1[rq * 4 + 1] * inv + qv1.y;
    ov1.z = o1[rq * 4 + 2] * inv + qv1.z;
    ov1.w = o1[rq * 4 + 3] * inv + qv1.w;
    *(float4*)(outp + base + 32 + d0) = ov1;
  }
}

extern "C" void kernel_launch(void* const* d_in, const int* in_sizes, int n_in,
                              void* d_out, int out_size, void* d_ws, size_t ws_size,
                              hipStream_t stream) {
  const float* query = (const float*)d_in[0];
  const float* key   = (const float*)d_in[1];
  const float* value = (const float*)d_in[2];
  const float* Wq = (const float*)d_in[3];
  const float* bq = (const float*)d_in[4];
  const float* Wk = (const float*)d_in[5];
  const float* bk = (const float*)d_in[6];
  const float* Wv = (const float*)d_in[7];
  const float* bv = (const float*)d_in[8];
  float* out = (float*)d_out;

  _Float16* ws = (_Float16*)d_ws;
  const size_t ACT = (size_t)Mm * Dd;
  const size_t WSZ = (size_t)Dd * Dd;
  _Float16* Xq   = ws;
  _Float16* Xk   = Xq + ACT;
  _Float16* Xv   = Xk + ACT;
  _Float16* Wtq  = Xv + ACT;
  _Float16* Wtk  = Wtq + WSZ;
  _Float16* Wtv  = Wtk + WSZ;
  _Float16* Qb   = Wtv + WSZ;
  _Float16* Kb   = Qb + ACT;
  _Float16* Vtmp = Kb + ACT;
  _Float16* VtT  = Vtmp + ACT;

  cvt_act<<<dim3(4096, 1, 3), dim3(256), 0, stream>>>(query, key, value, Xq, Xk, Xv);
  cvt_wt<<<dim3(16, 16, 3), dim3(256), 0, stream>>>(Wq, Wk, Wv, Wtq, Wtk, Wtv);
  gemm_qkv<<<dim3(64, 8, 3), dim3(256), 0, stream>>>(Xq, Xk, Xv, Wtq, Wtk, Wtv,
                                                     bq, bk, bv, Qb, Kb, Vtmp);
  transpose_v<<<dim3(32, 64), dim3(256), 0, stream>>>((const unsigned short*)Vtmp,
                                                      (unsigned short*)VtT);
  attn<<<dim3(64, 32), dim3(128), 0, stream>>>(Qb, Kb, VtT, query, out);
}

// Round 7
// 234.490 us; speedup vs baseline: 2.4786x; 1.4973x over previous
//
#include <hip/hip_runtime.h>
#include <hip/hip_bf16.h>
#include <stdint.h>

#define Bb 4
#define Ss 2048
#define Dd 1024
#define Hh 16
#define DK 64
#define BH 64
#define Mm 8192
#define KVT 64

typedef __attribute__((ext_vector_type(8))) _Float16 f16x8;
typedef __attribute__((ext_vector_type(2))) _Float16 f16x2;
typedef __attribute__((ext_vector_type(4))) float f32x4;
typedef __attribute__((ext_vector_type(16))) float f32x16;
typedef __attribute__((ext_vector_type(2))) unsigned uint2v;

__device__ __forceinline__ void gload16(const _Float16* g, _Float16* lds) {
  __builtin_amdgcn_global_load_lds((const __attribute__((address_space(1))) unsigned int*)g,
                                   (__attribute__((address_space(3))) unsigned int*)lds, 16, 0, 0);
}

// pack two f32 -> u32 of 2 f16 (RNE)
__device__ __forceinline__ unsigned pk2(float a, float b) {
  union { f16x2 h; unsigned u; } x;
  x.h[0] = (_Float16)a; x.h[1] = (_Float16)b;
  return x.u;
}

// ---------------- K0a: convert activations fp32 -> fp16 ----------------
__global__ __launch_bounds__(256) void cvt_act(const float* __restrict__ q,
                                               const float* __restrict__ k,
                                               const float* __restrict__ v,
                                               _Float16* __restrict__ xq,
                                               _Float16* __restrict__ xk,
                                               _Float16* __restrict__ xv) {
  const float* src = blockIdx.z == 0 ? q : (blockIdx.z == 1 ? k : v);
  _Float16* dst = blockIdx.z == 0 ? xq : (blockIdx.z == 1 ? xk : xv);
  int i = (blockIdx.x * 256 + threadIdx.x) * 8;
  float4 a = *(const float4*)(src + i);
  float4 b = *(const float4*)(src + i + 4);
  union { f16x8 v8; _Float16 h[8]; } o;
  o.h[0] = (_Float16)a.x; o.h[1] = (_Float16)a.y; o.h[2] = (_Float16)a.z; o.h[3] = (_Float16)a.w;
  o.h[4] = (_Float16)b.x; o.h[5] = (_Float16)b.y; o.h[6] = (_Float16)b.z; o.h[7] = (_Float16)b.w;
  *(f16x8*)(dst + i) = o.v8;
}

// ---------------- K0b: convert + transpose weights: Wt[n][k] = f16(W[k][n]) ----------------
__global__ __launch_bounds__(256) void cvt_wt(const float* __restrict__ wq,
                                              const float* __restrict__ wk,
                                              const float* __restrict__ wv,
                                              _Float16* __restrict__ tq,
                                              _Float16* __restrict__ tk,
                                              _Float16* __restrict__ tv) {
  const float* w = blockIdx.z == 0 ? wq : (blockIdx.z == 1 ? wk : wv);
  _Float16* o = blockIdx.z == 0 ? tq : (blockIdx.z == 1 ? tk : tv);
  __shared__ float tile[64][65];
  int k0 = blockIdx.x * 64;
  int n0 = blockIdx.y * 64;
  int t = threadIdx.x;
  int tr = t >> 4;
  int tc = (t & 15) * 4;
  for (int i = 0; i < 4; i++) {
    int r = i * 16 + tr;
    float4 val = *(const float4*)(w + (k0 + r) * Dd + n0 + tc);
    tile[r][tc + 0] = val.x; tile[r][tc + 1] = val.y;
    tile[r][tc + 2] = val.z; tile[r][tc + 3] = val.w;
  }
  __syncthreads();
  for (int i = 0; i < 2; i++) {
    int vdx = t + 256 * i;
    int rn = vdx >> 3;
    int c8 = (vdx & 7) * 8;
    union { f16x8 v8; _Float16 h[8]; } o2;
    for (int j = 0; j < 8; j++) o2.h[j] = (_Float16)tile[c8 + j][rn];
    *(f16x8*)(o + (n0 + rn) * Dd + k0 + c8) = o2.v8;
  }
}

// ---------------- K1: projection GEMM (m97 structure) ----------------
__global__ __launch_bounds__(256) void gemm_qkv(
    const _Float16* __restrict__ xq, const _Float16* __restrict__ xk,
    const _Float16* __restrict__ xv,
    const _Float16* __restrict__ wtq, const _Float16* __restrict__ wtk,
    const _Float16* __restrict__ wtv,
    const float* __restrict__ bq, const float* __restrict__ bk, const float* __restrict__ bv,
    _Float16* __restrict__ oq, _Float16* __restrict__ ok,
    _Float16* __restrict__ ov) {
  int z = blockIdx.z;
  const _Float16* A  = z == 0 ? xq  : (z == 1 ? xk  : xv);
  const _Float16* Bt = z == 0 ? wtq : (z == 1 ? wtk : wtv);
  const float* bias  = z == 0 ? bq  : (z == 1 ? bk  : bv);
  _Float16* out      = z == 0 ? oq  : (z == 1 ? ok  : ov);

  __shared__ _Float16 As[128 * 64];
  __shared__ _Float16 Bs[128 * 64];

  int tid = threadIdx.x;
  int w = tid >> 6;
  int l = tid & 63;
  int lr = l & 15, lk = l >> 4;
  int m0 = blockIdx.x * 128;
  int n0 = blockIdx.y * 128;
  int wr = (w >> 1) * 64;
  int wc = (w & 1) * 64;

  f32x4 acc[4][4] = {};

  for (int kt = 0; kt < Dd; kt += 64) {
    __syncthreads();
    for (int i = 0; i < 4; i++) {
      int fbase = i * 256 + w * 64;     // wave-uniform chunk base
      int f = fbase + l;
      int r = f >> 3, c = (f & 7) * 8;
      gload16(A + (m0 + r) * Dd + kt + c, &As[fbase * 8]);
      gload16(Bt + (n0 + r) * Dd + kt + c, &Bs[fbase * 8]);
    }
    __syncthreads();
    for (int kh = 0; kh < 2; kh++) {
      f16x8 af[4], bfr[4];
      for (int mi = 0; mi < 4; mi++)
        af[mi] = *(const f16x8*)&As[(wr + mi * 16 + lr) * 64 + kh * 32 + lk * 8];
      for (int ni = 0; ni < 4; ni++)
        bfr[ni] = *(const f16x8*)&Bs[(wc + ni * 16 + lr) * 64 + kh * 32 + lk * 8];
      for (int mi = 0; mi < 4; mi++)
        for (int ni = 0; ni < 4; ni++)
          acc[mi][ni] = __builtin_amdgcn_mfma_f32_16x16x32_f16(af[mi], bfr[ni], acc[mi][ni], 0, 0, 0);
    }
  }

  for (int mi = 0; mi < 4; mi++) {
    for (int ni = 0; ni < 4; ni++) {
      int n = n0 + wc + ni * 16 + lr;
      float bval = bias[n];
      int h = n >> 6, dk = n & 63;
      for (int j = 0; j < 4; j++) {
        int m = m0 + wr + mi * 16 + lk * 4 + j;
        int b = m >> 11, s = m & 2047;
        out[((b * Hh + h) * Ss + s) * DK + dk] = (_Float16)(acc[mi][ni][j] + bval);
      }
    }
  }
}

// ---------------- K2: transpose V: [bh][s][dk] -> [bh][dk][s] ----------------
__global__ __launch_bounds__(256) void transpose_v(const unsigned short* __restrict__ vin,
                                                   unsigned short* __restrict__ vout) {
  __shared__ unsigned short t[64][80];
  typedef __attribute__((ext_vector_type(8))) short s16x8;
  int bh = blockIdx.y;
  int s0 = blockIdx.x * 64;
  int tid = threadIdx.x;
  const unsigned short* vp = vin + bh * (Ss * DK);
  for (int i = 0; i < 2; i++) {
    int v = tid + 256 * i;
    int r = v >> 3, c8 = (v & 7) * 8;
    s16x8 val = *(const s16x8*)(vp + (s0 + r) * DK + c8);
    *(s16x8*)&t[r][c8] = val;
  }
  __syncthreads();
  unsigned short* op = vout + bh * (DK * Ss);
  for (int i = 0; i < 2; i++) {
    int v = tid + 256 * i;
    int rn = v >> 3;
    int c8 = (v & 7) * 8;
    union { s16x8 v8; unsigned short u[8]; } o2;
    for (int j = 0; j < 8; j++) o2.u[j] = t[c8 + j][rn];
    *(s16x8*)(op + rn * Ss + s0 + c8) = o2.v8;
  }
}

// ---------------- K3: flash attention, 32x32x16, LDS double-buffered K/V via global_load_lds ----------------
// Q,K: [bh][s][64] f16; Vt: [bh][64][s] f16; out fp32 [b,s,1024] = ctx + query.
// 1024 blocks x 4 waves (all resident, 4 blocks/CU). Block = 128 q-rows (32/wave),
// kv-tile = 64, double-buffered in LDS. Staging via global_load_lds (DMA: forces early
// issue, zero VGPR in flight); K [kv][dk] and V^T [d][kv] tiles XOR-swizzled
// (slot ^= row&7) via inverse-swizzled GLOBAL source + swizzled LDS reads (rule #21).
// QK swapped (S^T=mfma(K,Q)), lane-local softmax + defer-max, P in-register via
// permlane32_swap, PV swapped (ctx^T=mfma(V^T,P)). One barrier per tile.
__global__ __launch_bounds__(256) void attn(const _Float16* __restrict__ Qb,
                                            const _Float16* __restrict__ Kb,
                                            const _Float16* __restrict__ Vt,
                                            const float* __restrict__ query,
                                            float* __restrict__ outp) {
  __shared__ _Float16 Kl[2][KVT * 64];
  __shared__ _Float16 Vl[2][KVT * 64];

  int tid = threadIdx.x;
  int w = tid >> 6, l = tid & 63;
  int l31 = l & 31, hi = l >> 5;
  int bh = blockIdx.x;
  int q0 = blockIdx.y * 128 + w * 32;
  const _Float16* Qp = Qb + bh * (Ss * DK);
  const _Float16* Kp = Kb + bh * (Ss * DK);
  const _Float16* Vp = Vt + bh * (DK * Ss);

  // ---- staging geometry: per wave 2 K-instrs + 2 V-instrs, each covers 8 rows ----
  // lane l -> row base+(l>>3), LDS slot l&7; global source slot = (l&7)^((l>>3)&7)
  int srow = l >> 3;
  int sslot = (l & 7) ^ (srow & 7);
  int w16 = w * 16;
  const _Float16* ksrc0 = Kp + (w16 + srow) * DK + sslot * 8;
  const _Float16* ksrc1 = Kp + (w16 + 8 + srow) * DK + sslot * 8;
  const _Float16* vsrc0 = Vp + (w16 + srow) * Ss + sslot * 8;
  const _Float16* vsrc1 = Vp + (w16 + 8 + srow) * Ss + sslot * 8;

#define STAGE(KV0, BUF)                                                   \
  {                                                                       \
    gload16(ksrc0 + (KV0) * DK, &Kl[BUF][w16 * 64]);                      \
    gload16(ksrc1 + (KV0) * DK, &Kl[BUF][(w16 + 8) * 64]);                \
    gload16(vsrc0 + (KV0), &Vl[BUF][w16 * 64]);                           \
    gload16(vsrc1 + (KV0), &Vl[BUF][(w16 + 8) * 64]);                     \
  }

  // ---- Q as B-operand: col=q=q0+l31, k=dk=s*16+hi*8+i (from global, L2-hit) ----
  f16x8 qf[4];
#pragma unroll
  for (int s = 0; s < 4; s++)
    qf[s] = *(const f16x8*)(Qp + (q0 + l31) * DK + s * 16 + hi * 8);

  f32x16 o0 = {}, o1 = {};    // ctx^T: row d=dg*32+(r&3)+8*(r>>2)+4*hi, col q=l31
  float mrun = -1e30f, lrun = 0.f;

  // swizzled LDS read slots: row kv (or d) & 7 == l31 & 7 for all our reads
  int kv7 = l31 & 7;
  int rslot[4];
#pragma unroll
  for (int s = 0; s < 4; s++) rslot[s] = ((s * 2 + hi) ^ kv7) * 8;

  // prologue: stage tile 0
  STAGE(0, 0)
  __syncthreads();

  int cur = 0;
  for (int kv0 = 0; kv0 < Ss; kv0 += KVT) {
    // ---- issue staging for next tile (DMA; completes under this tile's compute) ----
    if (kv0 + KVT < Ss) STAGE(kv0 + KVT, cur ^ 1)

    // ---- QK^T (swapped): A=K rows kv from LDS, B=qf ----
    const _Float16* Kc = &Kl[cur][0];
    f32x16 s0 = {}, s1 = {};
#pragma unroll
    for (int s = 0; s < 4; s++) {
      f16x8 ka = *(const f16x8*)&Kc[l31 * 64 + rslot[s]];
      s0 = __builtin_amdgcn_mfma_f32_32x32x16_f16(ka, qf[s], s0, 0, 0, 0);
    }
#pragma unroll
    for (int s = 0; s < 4; s++) {
      f16x8 kb = *(const f16x8*)&Kc[(32 + l31) * 64 + rslot[s]];
      s1 = __builtin_amdgcn_mfma_f32_32x32x16_f16(kb, qf[s], s1, 0, 0, 0);
    }

    // ---- lane-local online softmax over 64 kv (lane owns q=q0+l31 half-row) ----
    float m8[8];
#pragma unroll
    for (int r = 0; r < 8; r++)
      m8[r] = fmaxf(fmaxf(s0[r], s0[r + 8]), fmaxf(s1[r], s1[r + 8]));
#pragma unroll
    for (int d = 4; d >= 1; d >>= 1)
#pragma unroll
      for (int r = 0; r < 4; r++) if (r < d) m8[r] = fmaxf(m8[r], m8[r + d]);
    float pm = fmaxf(m8[0], __shfl_xor(m8[0], 32));

    if (!__all(pm - mrun <= 8.f)) {        // defer-max (T13)
      float mn = fmaxf(mrun, pm);
      float sc_ = __expf(mrun - mn);
      mrun = mn;
      lrun *= sc_;
#pragma unroll
      for (int r = 0; r < 16; r++) { o0[r] *= sc_; o1[r] *= sc_; }
    }
#pragma unroll
    for (int r = 0; r < 16; r++) {
      s0[r] = __expf(s0[r] - mrun);
      s1[r] = __expf(s1[r] - mrun);
    }
    float sm[8];
#pragma unroll
    for (int r = 0; r < 8; r++) sm[r] = (s0[r] + s0[r + 8]) + (s1[r] + s1[r + 8]);
#pragma unroll
    for (int d = 4; d >= 1; d >>= 1)
#pragma unroll
      for (int r = 0; r < 4; r++) if (r < d) sm[r] += sm[r + d];
    lrun += sm[0] + __shfl_xor(sm[0], 32);

    // ---- pack P + permlane32_swap exchange + PV MFMA (V from LDS, swizzled) ----
    const _Float16* Vc = &Vl[cur][0];
#define PVSTEP(SRC, OFF, KST)                                                   \
    {                                                                           \
      unsigned a0 = pk2(SRC[(OFF) + 0], SRC[(OFF) + 1]);                        \
      unsigned a1 = pk2(SRC[(OFF) + 2], SRC[(OFF) + 3]);                        \
      unsigned b0 = pk2(SRC[(OFF) + 4], SRC[(OFF) + 5]);                        \
      unsigned b1 = pk2(SRC[(OFF) + 6], SRC[(OFF) + 7]);                        \
      uint2v r0 = __builtin_amdgcn_permlane32_swap(a0, b0, false, false);       \
      uint2v r1 = __builtin_amdgcn_permlane32_swap(a1, b1, false, false);       \
      union { unsigned u[4]; f16x8 v; } pf;                                     \
      pf.u[0] = r0[0]; pf.u[1] = r1[0]; pf.u[2] = r0[1]; pf.u[3] = r1[1];       \
      f16x8 v0 = *(const f16x8*)&Vc[l31 * 64 + rslot[KST]];                     \
      f16x8 v1 = *(const f16x8*)&Vc[(32 + l31) * 64 + rslot[KST]];              \
      o0 = __builtin_amdgcn_mfma_f32_32x32x16_f16(v0, pf.v, o0, 0, 0, 0);       \
      o1 = __builtin_amdgcn_mfma_f32_32x32x16_f16(v1, pf.v, o1, 0, 0, 0);       \
    }
    PVSTEP(s0, 0, 0)
    PVSTEP(s0, 8, 1)
    PVSTEP(s1, 0, 2)
    PVSTEP(s1, 8, 3)
#undef PVSTEP

    __syncthreads();   // all reads of buf[cur] done; staging of buf[cur^1] drained
    cur ^= 1;
  }

  // ---- epilogue: lane q=q0+l31; d = dg*32 + rq*8 + hi*4 + j ----
  int b = bh >> 4, h = bh & 15;
  float inv = 1.f / lrun;
  int base = (b * Ss + q0 + l31) * Dd + h * 64;
#pragma unroll
  for (int rq = 0; rq < 4; rq++) {
    int d0 = rq * 8 + hi * 4;
    float4 qv0 = *(const float4*)(query + base + d0);
    float4 ov0;
    ov0.x = o0[rq * 4 + 0] * inv + qv0.x;
    ov0.y = o0[rq * 4 + 1] * inv + qv0.y;
    ov0.z = o0[rq * 4 + 2] * inv + qv0.z;
    ov0.w = o0[rq * 4 + 3] * inv + qv0.w;
    *(float4*)(outp + base + d0) = ov0;
    float4 qv1 = *(const float4*)(query + base + 32 + d0);
    float4 ov1;
    ov1.x = o1[rq * 4 + 0] * inv + qv1.x;
    ov1.y = o1[rq * 4 + 1] * inv + qv1.y;
    ov1.z = o1[rq * 4 + 2] * inv + qv1.z;
    ov1.w = o1[rq * 4 + 3] * inv + qv1.w;
    *(float4*)(outp + base + 32 + d0) = ov1;
  }
#undef STAGE
}

extern "C" void kernel_launch(void* const* d_in, const int* in_sizes, int n_in,
                              void* d_out, int out_size, void* d_ws, size_t ws_size,
                              hipStream_t stream) {
  const float* query = (const float*)d_in[0];
  const float* key   = (const float*)d_in[1];
  const float* value = (const float*)d_in[2];
  const float* Wq = (const float*)d_in[3];
  const float* bq = (const float*)d_in[4];
  const float* Wk = (const float*)d_in[5];
  const float* bk = (const float*)d_in[6];
  const float* Wv = (const float*)d_in[7];
  const float* bv = (const float*)d_in[8];
  float* out = (float*)d_out;

  _Float16* ws = (_Float16*)d_ws;
  const size_t ACT = (size_t)Mm * Dd;
  const size_t WSZ = (size_t)Dd * Dd;
  _Float16* Xq   = ws;
  _Float16* Xk   = Xq + ACT;
  _Float16* Xv   = Xk + ACT;
  _Float16* Wtq  = Xv + ACT;
  _Float16* Wtk  = Wtq + WSZ;
  _Float16* Wtv  = Wtk + WSZ;
  _Float16* Qb   = Wtv + WSZ;
  _Float16* Kb   = Qb + ACT;
  _Float16* Vtmp = Kb + ACT;
  _Float16* VtT  = Vtmp + ACT;

  cvt_act<<<dim3(4096, 1, 3), dim3(256), 0, stream>>>(query, key, value, Xq, Xk, Xv);
  cvt_wt<<<dim3(16, 16, 3), dim3(256), 0, stream>>>(Wq, Wk, Wv, Wtq, Wtk, Wtv);
  gemm_qkv<<<dim3(64, 8, 3), dim3(256), 0, stream>>>(Xq, Xk, Xv, Wtq, Wtk, Wtv,
                                                     bq, bk, bv, Qb, Kb, Vtmp);
  transpose_v<<<dim3(32, 64), dim3(256), 0, stream>>>((const unsigned short*)Vtmp,
                                                      (unsigned short*)VtT);
  attn<<<dim3(64, 16), dim3(256), 0, stream>>>(Qb, Kb, VtT, query, out);
}